// Round 3
// baseline (633.528 us; speedup 1.0000x reference)
//
#include <hip/hip_runtime.h>
#include <math.h>

#define D_MODEL 512
#define NHEADS 8
#define DK 64
#define DFFN 2048

typedef __attribute__((ext_vector_type(8))) __bf16 bf16x8;
typedef __attribute__((ext_vector_type(4))) float floatx4;

// ============ LayerNorm: one block per row, out = bf16 ============
__global__ __launch_bounds__(256) void ln_kernel(
    const float* __restrict__ x, const float* __restrict__ alpha,
    const float* __restrict__ beta, __bf16* __restrict__ y) {
  int row = blockIdx.x;
  int t = threadIdx.x;
  const float* xr = x + (size_t)row * D_MODEL;
  float2 v = ((const float2*)xr)[t];
  __shared__ float rs[256], rq[256];
  rs[t] = v.x + v.y;
  rq[t] = v.x * v.x + v.y * v.y;
  __syncthreads();
  for (int o = 128; o > 0; o >>= 1) {
    if (t < o) { rs[t] += rs[t + o]; rq[t] += rq[t + o]; }
    __syncthreads();
  }
  float mu = rs[0] * (1.0f / D_MODEL);
  // ddof=1 variance; denominator (sd + eps) matches jnp.std + EPS
  float var = (rq[0] - (float)D_MODEL * mu * mu) * (1.0f / (D_MODEL - 1));
  float inv = 1.0f / (sqrtf(fmaxf(var, 0.0f)) + 1e-6f);
  float2 a2 = ((const float2*)alpha)[t];
  float2 b2 = ((const float2*)beta)[t];
  union { __bf16 h2[2]; unsigned int u; } pk;
  pk.h2[0] = (__bf16)(a2.x * (v.x - mu) * inv + b2.x);
  pk.h2[1] = (__bf16)(a2.y * (v.y - mu) * inv + b2.y);
  *(unsigned int*)(y + (size_t)row * D_MODEL + 2 * t) = pk.u;
}

// ============ fp32 -> bf16 cast, 6 segments, vectorized x4 ============
struct Seg { const float* src; __bf16* dst; int n4; };
struct Segs6 { Seg s[6]; };
__global__ __launch_bounds__(256) void cast6(Segs6 cs) {
  Seg sg = cs.s[blockIdx.y];
  int stride = gridDim.x * 256;
  for (int idx = blockIdx.x * 256 + threadIdx.x; idx < sg.n4; idx += stride) {
    float4 f = ((const float4*)sg.src)[idx];
    union { __bf16 h[4]; uint2 u; } pk;
    pk.h[0] = (__bf16)f.x; pk.h[1] = (__bf16)f.y;
    pk.h[2] = (__bf16)f.z; pk.h[3] = (__bf16)f.w;
    ((uint2*)sg.dst)[idx] = pk.u;
  }
}

__global__ __launch_bounds__(256) void pack_bias(
    const float* __restrict__ bq, const float* __restrict__ bk,
    const float* __restrict__ bv, float* __restrict__ dst) {
  int idx = blockIdx.x * 256 + threadIdx.x;
  if (idx >= 3 * D_MODEL) return;
  float v = idx < 512 ? bq[idx] : (idx < 1024 ? bk[idx - 512] : bv[idx - 1024]);
  dst[idx] = v;
}

// ============ Wave-level bf16 MFMA GEMM ============
// C[m,n] = sum_k A[m,k]*B[n,k] + bias[n] (+res) (opt relu, opt bf16 out)
// One wave per 32x32 tile, 2x2 frags of 16x16x32, direct L2 loads (no LDS).
template <int RELU, int OUT_BF16>
__global__ __launch_bounds__(64) void wave_gemm(
    const __bf16* __restrict__ A, int lda, const __bf16* __restrict__ B, int ldb,
    const float* __restrict__ bias, const float* __restrict__ res,
    void* __restrict__ Cv, int N, int K) {
  int lane = threadIdx.x;
  int r16 = lane & 15;
  int ko = (lane >> 4) * 8;
  int m0 = blockIdx.y * 32, n0 = blockIdx.x * 32;
  const __bf16* A0 = A + (size_t)(m0 + r16) * lda + ko;
  const __bf16* A1 = A0 + (size_t)16 * lda;
  const __bf16* B0 = B + (size_t)(n0 + r16) * ldb + ko;
  const __bf16* B1 = B0 + (size_t)16 * ldb;
  floatx4 acc00 = {0.f, 0.f, 0.f, 0.f};
  floatx4 acc01 = acc00, acc10 = acc00, acc11 = acc00;
#pragma unroll 4
  for (int k0 = 0; k0 < K; k0 += 32) {
    bf16x8 a0 = *(const bf16x8*)(A0 + k0);
    bf16x8 a1 = *(const bf16x8*)(A1 + k0);
    bf16x8 b0 = *(const bf16x8*)(B0 + k0);
    bf16x8 b1 = *(const bf16x8*)(B1 + k0);
    acc00 = __builtin_amdgcn_mfma_f32_16x16x32_bf16(a0, b0, acc00, 0, 0, 0);
    acc01 = __builtin_amdgcn_mfma_f32_16x16x32_bf16(a0, b1, acc01, 0, 0, 0);
    acc10 = __builtin_amdgcn_mfma_f32_16x16x32_bf16(a1, b0, acc10, 0, 0, 0);
    acc11 = __builtin_amdgcn_mfma_f32_16x16x32_bf16(a1, b1, acc11, 0, 0, 0);
  }
  int col = lane & 15, rb = (lane >> 4) * 4;
  floatx4 accs[2][2] = {{acc00, acc01}, {acc10, acc11}};
#pragma unroll
  for (int i = 0; i < 2; ++i) {
#pragma unroll
    for (int j = 0; j < 2; ++j) {
#pragma unroll
      for (int r = 0; r < 4; ++r) {
        int row = m0 + i * 16 + rb + r;
        int cc = n0 + j * 16 + col;
        float v = accs[i][j][r] + bias[cc];
        if (res) v += res[(size_t)row * N + cc];
        if (RELU) v = fmaxf(v, 0.0f);
        if (OUT_BF16)
          ((__bf16*)Cv)[(size_t)row * N + cc] = (__bf16)v;
        else
          ((float*)Cv)[(size_t)row * N + cc] = v;
      }
    }
  }
}

// ============ Attention phase 1: scores ============
// Grid (jb=4, i=s, b). Block 256 thr = 4 waves; wave w handles 16 j's.
// sc_out layout: [tok_i][h][s] fp32.
__global__ __launch_bounds__(256) void attn_scores(
    const float* __restrict__ qkv, int ldq, const float* __restrict__ cbk,
    float* __restrict__ sc_out, int s) {
  int jb = blockIdx.x;
  int i = blockIdx.y;
  int b = blockIdx.z;
  int t = threadIdx.x;
  int w = t >> 6, lane = t & 63, h = lane >> 3;
  __shared__ float scl[64][9];  // [jj][h], padded
  size_t tok_i = (size_t)(b * s + i);
  const float* qp = qkv + tok_i * ldq + lane * 8;
  float4 q0 = *(const float4*)qp;
  float4 q1 = *(const float4*)(qp + 4);
  int jbase = jb * 64 + w * 16;
#pragma unroll 4
  for (int jj = 0; jj < 16; ++jj) {
    int j = jbase + jj;
    size_t tok_j = (size_t)(b * s + j);
    const float* kp = qkv + tok_j * ldq + 512 + lane * 8;
    const float* cp = cbk + (tok_j * s + i) * (size_t)D_MODEL + lane * 8;
    float4 k0 = *(const float4*)kp;
    float4 k1 = *(const float4*)(kp + 4);
    float4 c0 = *(const float4*)cp;
    float4 c1 = *(const float4*)(cp + 4);
    float d = q0.x * (k0.x + c0.x) + q0.y * (k0.y + c0.y) +
              q0.z * (k0.z + c0.z) + q0.w * (k0.w + c0.w) +
              q1.x * (k1.x + c1.x) + q1.y * (k1.y + c1.y) +
              q1.z * (k1.z + c1.z) + q1.w * (k1.w + c1.w);
    d += __shfl_xor(d, 1);
    d += __shfl_xor(d, 2);
    d += __shfl_xor(d, 4);
    if ((lane & 7) == 0) scl[w * 16 + jj][h] = d * 0.125f;
  }
  __syncthreads();
  // Coalesced write-out: 8 h-rows x 64 contiguous j
  int hh = t >> 5;
  int jj2 = (t & 31) * 2;
  float2 v2;
  v2.x = scl[jj2][hh];
  v2.y = scl[jj2 + 1][hh];
  *(float2*)(sc_out + (tok_i * NHEADS + hh) * s + jb * 64 + jj2) = v2;
}

// ============ Attention phase 2: softmax (in-place, normalized) ============
// One wave per (tok,h) row of s=256; block=4 rows.
__global__ __launch_bounds__(256) void attn_softmax(
    float* __restrict__ sc, const int* __restrict__ mask, int s) {
  int row = blockIdx.x * 4 + (threadIdx.x >> 6);  // tok*8+h
  int lane = threadIdx.x & 63;
  float* p = sc + (size_t)row * s;
  float4 v = ((float4*)p)[lane];
  if (mask[row >> 3] == 1) { v.x = -1e9f; v.y = -1e9f; v.z = -1e9f; v.w = -1e9f; }
  float mx = fmaxf(fmaxf(v.x, v.y), fmaxf(v.z, v.w));
  for (int m = 1; m < 64; m <<= 1) mx = fmaxf(mx, __shfl_xor(mx, m));
  float e0 = expf(v.x - mx), e1 = expf(v.y - mx);
  float e2 = expf(v.z - mx), e3 = expf(v.w - mx);
  float ls = e0 + e1 + e2 + e3;
  for (int m = 1; m < 64; m <<= 1) ls += __shfl_xor(ls, m);
  float inv = 1.0f / ls;
  float4 o = {e0 * inv, e1 * inv, e2 * inv, e3 * inv};
  ((float4*)p)[lane] = o;
}

// ============ Attention phase 3: PV partial ============
// Grid (jb=4, i=s, b). part layout: [tok_i][jb][D_MODEL] fp32.
__global__ __launch_bounds__(256) void attn_pv(
    const float* __restrict__ qkv, int ldq, const float* __restrict__ cbv,
    const float* __restrict__ p, float* __restrict__ part, int s) {
  int jb = blockIdx.x;
  int i = blockIdx.y;
  int b = blockIdx.z;
  int t = threadIdx.x;
  int w = t >> 6, lane = t & 63, h = lane >> 3;
  __shared__ float pl[NHEADS][64];
  __shared__ float accs[4][D_MODEL];
  size_t tok_i = (size_t)(b * s + i);
  {  // stage this block's p chunk: 8 h x 64 j
    int hh = t >> 5;
    int jj2 = (t & 31) * 2;
    float2 pv = *(const float2*)(p + (tok_i * NHEADS + hh) * s + jb * 64 + jj2);
    pl[hh][jj2] = pv.x;
    pl[hh][jj2 + 1] = pv.y;
  }
  __syncthreads();
  float4 a0 = {0.f, 0.f, 0.f, 0.f};
  float4 a1 = {0.f, 0.f, 0.f, 0.f};
  int jbase = jb * 64 + w * 16;
#pragma unroll 4
  for (int jj = 0; jj < 16; ++jj) {
    int j = jbase + jj;
    size_t tok_j = (size_t)(b * s + j);
    const float* vp = qkv + tok_j * ldq + 1024 + lane * 8;
    const float* cp = cbv + (tok_j * s + i) * (size_t)D_MODEL + lane * 8;
    float4 v0 = *(const float4*)vp;
    float4 v1 = *(const float4*)(vp + 4);
    float4 c0 = *(const float4*)cp;
    float4 c1 = *(const float4*)(cp + 4);
    float pj = pl[h][w * 16 + jj];
    a0.x += pj * (v0.x + c0.x); a0.y += pj * (v0.y + c0.y);
    a0.z += pj * (v0.z + c0.z); a0.w += pj * (v0.w + c0.w);
    a1.x += pj * (v1.x + c1.x); a1.y += pj * (v1.y + c1.y);
    a1.z += pj * (v1.z + c1.z); a1.w += pj * (v1.w + c1.w);
  }
  *(float4*)&accs[w][lane * 8] = a0;
  *(float4*)&accs[w][lane * 8 + 4] = a1;
  __syncthreads();
  int d0 = t * 2;
  float2 o;
  o.x = accs[0][d0] + accs[1][d0] + accs[2][d0] + accs[3][d0];
  o.y = accs[0][d0 + 1] + accs[1][d0 + 1] + accs[2][d0 + 1] + accs[3][d0 + 1];
  *(float2*)(part + (tok_i * 4 + jb) * (size_t)D_MODEL + d0) = o;
}

// ============ Attention phase 4: reduce partials -> concat bf16 ============
__global__ __launch_bounds__(256) void attn_reduce(
    const float* __restrict__ part, __bf16* __restrict__ concat) {
  size_t tok = blockIdx.x;
  int d0 = threadIdx.x * 2;
  const float* pp = part + tok * 4 * D_MODEL + d0;
  float2 v0 = *(const float2*)(pp);
  float2 v1 = *(const float2*)(pp + D_MODEL);
  float2 v2 = *(const float2*)(pp + 2 * D_MODEL);
  float2 v3 = *(const float2*)(pp + 3 * D_MODEL);
  union { __bf16 h2[2]; unsigned int u; } pk;
  pk.h2[0] = (__bf16)(v0.x + v1.x + v2.x + v3.x);
  pk.h2[1] = (__bf16)(v0.y + v1.y + v2.y + v3.y);
  *(unsigned int*)(concat + tok * D_MODEL + d0) = pk.u;
}

// ============ Host launch ============
extern "C" void kernel_launch(void* const* d_in, const int* in_sizes, int n_in,
                              void* d_out, int out_size, void* d_ws, size_t ws_size,
                              hipStream_t stream) {
  const float* x      = (const float*)d_in[0];
  const float* cbk    = (const float*)d_in[1];
  const float* cbv    = (const float*)d_in[2];
  const int*   mask   = (const int*)d_in[3];
  const float* Wq     = (const float*)d_in[4];
  const float* bq     = (const float*)d_in[5];
  const float* Wk     = (const float*)d_in[6];
  const float* bk     = (const float*)d_in[7];
  const float* Wv     = (const float*)d_in[8];
  const float* bv     = (const float*)d_in[9];
  const float* Wo     = (const float*)d_in[10];
  const float* bo     = (const float*)d_in[11];
  const float* alpha1 = (const float*)d_in[12];
  const float* beta1  = (const float*)d_in[13];
  const float* alpha2 = (const float*)d_in[14];
  const float* beta2  = (const float*)d_in[15];
  const float* W1     = (const float*)d_in[16];
  const float* b1     = (const float*)d_in[17];
  const float* W2     = (const float*)d_in[18];
  const float* b2     = (const float*)d_in[19];

  int bs = in_sizes[0] / D_MODEL;       // 512 tokens
  int s  = in_sizes[1] / in_sizes[0];   // 256
  int b  = bs / s;                      // 2

  char* wp = (char*)d_ws;
  auto carve = [&](size_t bytes) {
    char* p = wp;
    wp += (bytes + 255) & ~(size_t)255;
    return p;
  };
  __bf16* x2    = (__bf16*)carve((size_t)bs * D_MODEL * 2);
  __bf16* wqkv  = (__bf16*)carve((size_t)3 * D_MODEL * D_MODEL * 2);
  __bf16* wo_b  = (__bf16*)carve((size_t)D_MODEL * D_MODEL * 2);
  __bf16* w1_b  = (__bf16*)carve((size_t)DFFN * D_MODEL * 2);
  __bf16* w2_b  = (__bf16*)carve((size_t)D_MODEL * DFFN * 2);
  float*  bqkv  = (float*)carve((size_t)3 * D_MODEL * 4);
  float*  qkv   = (float*)carve((size_t)bs * 3 * D_MODEL * 4);
  float*  sc_ws = (float*)carve((size_t)bs * NHEADS * s * 4);   // 4 MB
  float*  partw = (float*)carve((size_t)bs * 4 * D_MODEL * 4);  // 4 MB
  __bf16* conc  = (__bf16*)carve((size_t)bs * D_MODEL * 2);
  float*  xres  = (float*)carve((size_t)bs * D_MODEL * 4);
  __bf16* x2b   = (__bf16*)carve((size_t)bs * D_MODEL * 2);
  __bf16* f1    = (__bf16*)carve((size_t)bs * DFFN * 2);

  // 1. Weight casts (Wq/Wk/Wv packed into [1536][512]) + bias pack
  Segs6 cs;
  cs.s[0] = {Wq, wqkv,                         D_MODEL * D_MODEL / 4};
  cs.s[1] = {Wk, wqkv + D_MODEL * D_MODEL,     D_MODEL * D_MODEL / 4};
  cs.s[2] = {Wv, wqkv + 2 * D_MODEL * D_MODEL, D_MODEL * D_MODEL / 4};
  cs.s[3] = {Wo, wo_b, D_MODEL * D_MODEL / 4};
  cs.s[4] = {W1, w1_b, DFFN * D_MODEL / 4};
  cs.s[5] = {W2, w2_b, D_MODEL * DFFN / 4};
  cast6<<<dim3(256, 6), 256, 0, stream>>>(cs);
  pack_bias<<<6, 256, 0, stream>>>(bq, bk, bv, bqkv);

  // 2. LN1 -> bf16
  ln_kernel<<<bs, 256, 0, stream>>>(x, alpha1, beta1, x2);

  // 3. Fused QKV GEMM -> qkv [512][1536] fp32
  wave_gemm<0, 0><<<dim3(3 * D_MODEL / 32, bs / 32), 64, 0, stream>>>(
      x2, D_MODEL, wqkv, D_MODEL, bqkv, nullptr, qkv, 3 * D_MODEL, D_MODEL);

  // 4. Attention: scores -> softmax -> PV partials -> reduce
  attn_scores<<<dim3(4, s, b), 256, 0, stream>>>(qkv, 3 * D_MODEL, cbk, sc_ws, s);
  attn_softmax<<<bs * NHEADS / 4, 256, 0, stream>>>(sc_ws, mask, s);
  attn_pv<<<dim3(4, s, b), 256, 0, stream>>>(qkv, 3 * D_MODEL, cbv, sc_ws, partw, s);
  attn_reduce<<<bs, 256, 0, stream>>>(partw, conc);

  // 5. Wo GEMM + residual(x) -> xres fp32
  wave_gemm<0, 0><<<dim3(D_MODEL / 32, bs / 32), 64, 0, stream>>>(
      conc, D_MODEL, wo_b, D_MODEL, bo, x, xres, D_MODEL, D_MODEL);

  // 6. LN2 -> bf16
  ln_kernel<<<bs, 256, 0, stream>>>(xres, alpha2, beta2, x2b);

  // 7. FFN1 + ReLU -> f1 bf16
  wave_gemm<1, 1><<<dim3(DFFN / 32, bs / 32), 64, 0, stream>>>(
      x2b, D_MODEL, w1_b, D_MODEL, b1, nullptr, f1, DFFN, D_MODEL);

  // 8. FFN2 + bias + residual(xres) -> d_out fp32
  wave_gemm<0, 0><<<dim3(D_MODEL / 32, bs / 32), 64, 0, stream>>>(
      f1, DFFN, w2_b, DFFN, b2, xres, d_out, D_MODEL, DFFN);
}

// Round 5
// 628.981 us; speedup vs baseline: 1.0072x; 1.0072x over previous
//
#include <hip/hip_runtime.h>
#include <math.h>

#define D_MODEL 512
#define NHEADS 8
#define DK 64
#define DFFN 2048

typedef __attribute__((ext_vector_type(8))) __bf16 bf16x8;
typedef __attribute__((ext_vector_type(4))) float floatx4;

// Nontemporal 16-B load via native clang vector (HIP float4 is a class and
// is rejected by the builtin).
static __device__ inline float4 ntload4(const float* p) {
  floatx4 v = __builtin_nontemporal_load((const floatx4*)p);
  return make_float4(v.x, v.y, v.z, v.w);
}

// ============ LayerNorm: one block per row, out = bf16 ============
__global__ __launch_bounds__(256) void ln_kernel(
    const float* __restrict__ x, const float* __restrict__ alpha,
    const float* __restrict__ beta, __bf16* __restrict__ y) {
  int row = blockIdx.x;
  int t = threadIdx.x;
  const float* xr = x + (size_t)row * D_MODEL;
  float2 v = ((const float2*)xr)[t];
  __shared__ float rs[256], rq[256];
  rs[t] = v.x + v.y;
  rq[t] = v.x * v.x + v.y * v.y;
  __syncthreads();
  for (int o = 128; o > 0; o >>= 1) {
    if (t < o) { rs[t] += rs[t + o]; rq[t] += rq[t + o]; }
    __syncthreads();
  }
  float mu = rs[0] * (1.0f / D_MODEL);
  // ddof=1 variance; denominator (sd + eps) matches jnp.std + EPS
  float var = (rq[0] - (float)D_MODEL * mu * mu) * (1.0f / (D_MODEL - 1));
  float inv = 1.0f / (sqrtf(fmaxf(var, 0.0f)) + 1e-6f);
  float2 a2 = ((const float2*)alpha)[t];
  float2 b2 = ((const float2*)beta)[t];
  union { __bf16 h2[2]; unsigned int u; } pk;
  pk.h2[0] = (__bf16)(a2.x * (v.x - mu) * inv + b2.x);
  pk.h2[1] = (__bf16)(a2.y * (v.y - mu) * inv + b2.y);
  *(unsigned int*)(y + (size_t)row * D_MODEL + 2 * t) = pk.u;
}

// ============ fp32 -> bf16 cast, 6 segments ============
struct Seg { const float* src; __bf16* dst; int n4; };
struct Segs6 { Seg s[6]; };
__global__ __launch_bounds__(256) void cast6(Segs6 cs) {
  Seg sg = cs.s[blockIdx.y];
  int stride = gridDim.x * 256;
  for (int idx = blockIdx.x * 256 + threadIdx.x; idx < sg.n4; idx += stride) {
    float4 f = ((const float4*)sg.src)[idx];
    union { __bf16 h[4]; uint2 u; } pk;
    pk.h[0] = (__bf16)f.x; pk.h[1] = (__bf16)f.y;
    pk.h[2] = (__bf16)f.z; pk.h[3] = (__bf16)f.w;
    ((uint2*)sg.dst)[idx] = pk.u;
  }
}

// ============ Wave-level bf16 MFMA GEMM ============
// C[m,n] = sum_k A[m,k]*B[n,k] + bias (+res) (opt relu/bf16-out).
// BIAS3: bias selected from 3 concatenated 512-wide segments (QKV).
template <int RELU, int OUT_BF16, int BIAS3>
__global__ __launch_bounds__(64) void wave_gemm(
    const __bf16* __restrict__ A, int lda, const __bf16* __restrict__ B, int ldb,
    const float* __restrict__ bias, const float* __restrict__ bias2,
    const float* __restrict__ bias3, const float* __restrict__ res,
    void* __restrict__ Cv, int N, int K) {
  int lane = threadIdx.x;
  int r16 = lane & 15;
  int ko = (lane >> 4) * 8;
  int m0 = blockIdx.y * 32, n0 = blockIdx.x * 32;
  const __bf16* A0 = A + (size_t)(m0 + r16) * lda + ko;
  const __bf16* A1 = A0 + (size_t)16 * lda;
  const __bf16* B0 = B + (size_t)(n0 + r16) * ldb + ko;
  const __bf16* B1 = B0 + (size_t)16 * ldb;
  floatx4 acc00 = {0.f, 0.f, 0.f, 0.f};
  floatx4 acc01 = acc00, acc10 = acc00, acc11 = acc00;
#pragma unroll 4
  for (int k0 = 0; k0 < K; k0 += 32) {
    bf16x8 a0 = *(const bf16x8*)(A0 + k0);
    bf16x8 a1 = *(const bf16x8*)(A1 + k0);
    bf16x8 b0 = *(const bf16x8*)(B0 + k0);
    bf16x8 b1 = *(const bf16x8*)(B1 + k0);
    acc00 = __builtin_amdgcn_mfma_f32_16x16x32_bf16(a0, b0, acc00, 0, 0, 0);
    acc01 = __builtin_amdgcn_mfma_f32_16x16x32_bf16(a0, b1, acc01, 0, 0, 0);
    acc10 = __builtin_amdgcn_mfma_f32_16x16x32_bf16(a1, b0, acc10, 0, 0, 0);
    acc11 = __builtin_amdgcn_mfma_f32_16x16x32_bf16(a1, b1, acc11, 0, 0, 0);
  }
  int col = lane & 15, rb = (lane >> 4) * 4;
  floatx4 accs[2][2] = {{acc00, acc01}, {acc10, acc11}};
#pragma unroll
  for (int i = 0; i < 2; ++i) {
#pragma unroll
    for (int j = 0; j < 2; ++j) {
      int cc = n0 + j * 16 + col;
      float bv_;
      if (BIAS3)
        bv_ = cc < 512 ? bias[cc] : (cc < 1024 ? bias2[cc - 512] : bias3[cc - 1024]);
      else
        bv_ = bias[cc];
#pragma unroll
      for (int r = 0; r < 4; ++r) {
        int row = m0 + i * 16 + rb + r;
        float v = accs[i][j][r] + bv_;
        if (res) v += res[(size_t)row * N + cc];
        if (RELU) v = fmaxf(v, 0.0f);
        if (OUT_BF16)
          ((__bf16*)Cv)[(size_t)row * N + cc] = (__bf16)v;
        else
          ((float*)Cv)[(size_t)row * N + cc] = v;
      }
    }
  }
}

// ============ Attention phase 1: scores + per-chunk softmax stats ============
// Grid (jb=4, i=s, b). sc_out: [tok][h][s] masked+scaled fp32.
// stats: [tok][h][jb] {chunk_max, chunk_sumexp}.
__global__ __launch_bounds__(256) void attn_scores(
    const float* __restrict__ qkv, int ldq, const float* __restrict__ cbk,
    const int* __restrict__ mask, float* __restrict__ sc_out,
    float2* __restrict__ stats, int s) {
  int jb = blockIdx.x;
  int i = blockIdx.y;
  int b = blockIdx.z;
  int t = threadIdx.x;
  int w = t >> 6, lane = t & 63, h = lane >> 3;
  __shared__ float scl[64][9];  // [jj][h], padded
  size_t tok_i = (size_t)(b * s + i);
  const float* qp = qkv + tok_i * ldq + lane * 8;
  float4 q0 = *(const float4*)qp;
  float4 q1 = *(const float4*)(qp + 4);
  int jbase = jb * 64 + w * 16;
#pragma unroll 4
  for (int jj = 0; jj < 16; ++jj) {
    int j = jbase + jj;
    size_t tok_j = (size_t)(b * s + j);
    const float* kp = qkv + tok_j * ldq + 512 + lane * 8;
    const float* cp = cbk + (tok_j * s + i) * (size_t)D_MODEL + lane * 8;
    float4 k0 = *(const float4*)kp;
    float4 k1 = *(const float4*)(kp + 4);
    float4 c0 = ntload4(cp);
    float4 c1 = ntload4(cp + 4);
    float d = q0.x * (k0.x + c0.x) + q0.y * (k0.y + c0.y) +
              q0.z * (k0.z + c0.z) + q0.w * (k0.w + c0.w) +
              q1.x * (k1.x + c1.x) + q1.y * (k1.y + c1.y) +
              q1.z * (k1.z + c1.z) + q1.w * (k1.w + c1.w);
    d += __shfl_xor(d, 1);
    d += __shfl_xor(d, 2);
    d += __shfl_xor(d, 4);
    if ((lane & 7) == 0) scl[w * 16 + jj][h] = d * 0.125f;
  }
  __syncthreads();
  // Write-out + stats: 32 threads per head row.
  int hh = t >> 5;
  int jj2 = (t & 31) * 2;
  bool masked = (mask[b * s + i] == 1);
  float v0 = masked ? -1e9f : scl[jj2][hh];
  float v1 = masked ? -1e9f : scl[jj2 + 1][hh];
  float2 v2 = {v0, v1};
  *(float2*)(sc_out + (tok_i * NHEADS + hh) * s + jb * 64 + jj2) = v2;
  float mx = fmaxf(v0, v1);
  for (int m = 1; m < 32; m <<= 1) mx = fmaxf(mx, __shfl_xor(mx, m, 32));
  float se = expf(v0 - mx) + expf(v1 - mx);
  for (int m = 1; m < 32; m <<= 1) se += __shfl_xor(se, m, 32);
  if ((t & 31) == 0) {
    float2 st = {mx, se};
    stats[(tok_i * NHEADS + hh) * 4 + jb] = st;
  }
}

// ============ Attention phase 2: PV with inline softmax finish ============
// Grid (jb=4, i=s, b). part: [tok][jb][D_MODEL] fp32.
__global__ __launch_bounds__(256) void attn_pv(
    const float* __restrict__ qkv, int ldq, const float* __restrict__ cbv,
    const float* __restrict__ sc, const float2* __restrict__ stats,
    float* __restrict__ part, int s) {
  int jb = blockIdx.x;
  int i = blockIdx.y;
  int b = blockIdx.z;
  int t = threadIdx.x;
  int w = t >> 6, lane = t & 63, h = lane >> 3;
  __shared__ float2 sst[NHEADS][4];
  __shared__ float sM[NHEADS], sInvS[NHEADS];
  __shared__ float pl[NHEADS][64];
  __shared__ float accs[4][D_MODEL];
  size_t tok_i = (size_t)(b * s + i);
  if (t < 32) sst[t >> 2][t & 3] = stats[(tok_i * NHEADS + (t >> 2)) * 4 + (t & 3)];
  __syncthreads();
  if (t < NHEADS) {
    float M = -1e30f;
#pragma unroll
    for (int q = 0; q < 4; ++q) M = fmaxf(M, sst[t][q].x);
    float S = 0.f;
#pragma unroll
    for (int q = 0; q < 4; ++q) S += sst[t][q].y * expf(sst[t][q].x - M);
    sM[t] = M;
    sInvS[t] = 1.0f / S;
  }
  __syncthreads();
  {  // stage normalized p for this jb chunk: 8 h x 64 j
    int hh = t >> 5;
    int jj2 = (t & 31) * 2;
    float2 sv = *(const float2*)(sc + (tok_i * NHEADS + hh) * s + jb * 64 + jj2);
    pl[hh][jj2]     = expf(sv.x - sM[hh]) * sInvS[hh];
    pl[hh][jj2 + 1] = expf(sv.y - sM[hh]) * sInvS[hh];
  }
  __syncthreads();
  float4 a0 = {0.f, 0.f, 0.f, 0.f};
  float4 a1 = {0.f, 0.f, 0.f, 0.f};
  int jbase = jb * 64 + w * 16;
#pragma unroll 4
  for (int jj = 0; jj < 16; ++jj) {
    int j = jbase + jj;
    size_t tok_j = (size_t)(b * s + j);
    const float* vp = qkv + tok_j * ldq + 1024 + lane * 8;
    const float* cp = cbv + (tok_j * s + i) * (size_t)D_MODEL + lane * 8;
    float4 v0 = *(const float4*)vp;
    float4 v1 = *(const float4*)(vp + 4);
    float4 c0 = ntload4(cp);
    float4 c1 = ntload4(cp + 4);
    float pj = pl[h][w * 16 + jj];
    a0.x += pj * (v0.x + c0.x); a0.y += pj * (v0.y + c0.y);
    a0.z += pj * (v0.z + c0.z); a0.w += pj * (v0.w + c0.w);
    a1.x += pj * (v1.x + c1.x); a1.y += pj * (v1.y + c1.y);
    a1.z += pj * (v1.z + c1.z); a1.w += pj * (v1.w + c1.w);
  }
  *(float4*)&accs[w][lane * 8] = a0;
  *(float4*)&accs[w][lane * 8 + 4] = a1;
  __syncthreads();
  int d0 = t * 2;
  float2 o;
  o.x = accs[0][d0] + accs[1][d0] + accs[2][d0] + accs[3][d0];
  o.y = accs[0][d0 + 1] + accs[1][d0 + 1] + accs[2][d0 + 1] + accs[3][d0 + 1];
  *(float2*)(part + (tok_i * 4 + jb) * (size_t)D_MODEL + d0) = o;
}

// ============ Attention phase 3: reduce partials -> concat bf16 ============
__global__ __launch_bounds__(256) void attn_reduce(
    const float* __restrict__ part, __bf16* __restrict__ concat) {
  size_t tok = blockIdx.x;
  int d0 = threadIdx.x * 2;
  const float* pp = part + tok * 4 * D_MODEL + d0;
  float2 v0 = *(const float2*)(pp);
  float2 v1 = *(const float2*)(pp + D_MODEL);
  float2 v2 = *(const float2*)(pp + 2 * D_MODEL);
  float2 v3 = *(const float2*)(pp + 3 * D_MODEL);
  union { __bf16 h2[2]; unsigned int u; } pk;
  pk.h2[0] = (__bf16)(v0.x + v1.x + v2.x + v3.x);
  pk.h2[1] = (__bf16)(v0.y + v1.y + v2.y + v3.y);
  *(unsigned int*)(concat + tok * D_MODEL + d0) = pk.u;
}

// ============ Host launch ============
extern "C" void kernel_launch(void* const* d_in, const int* in_sizes, int n_in,
                              void* d_out, int out_size, void* d_ws, size_t ws_size,
                              hipStream_t stream) {
  const float* x      = (const float*)d_in[0];
  const float* cbk    = (const float*)d_in[1];
  const float* cbv    = (const float*)d_in[2];
  const int*   mask   = (const int*)d_in[3];
  const float* Wq     = (const float*)d_in[4];
  const float* bq     = (const float*)d_in[5];
  const float* Wk     = (const float*)d_in[6];
  const float* bk     = (const float*)d_in[7];
  const float* Wv     = (const float*)d_in[8];
  const float* bv     = (const float*)d_in[9];
  const float* Wo     = (const float*)d_in[10];
  const float* bo     = (const float*)d_in[11];
  const float* alpha1 = (const float*)d_in[12];
  const float* beta1  = (const float*)d_in[13];
  const float* alpha2 = (const float*)d_in[14];
  const float* beta2  = (const float*)d_in[15];
  const float* W1     = (const float*)d_in[16];
  const float* b1     = (const float*)d_in[17];
  const float* W2     = (const float*)d_in[18];
  const float* b2     = (const float*)d_in[19];

  int bs = in_sizes[0] / D_MODEL;       // 512 tokens
  int s  = in_sizes[1] / in_sizes[0];   // 256
  int b  = bs / s;                      // 2

  char* wp = (char*)d_ws;
  auto carve = [&](size_t bytes) {
    char* p = wp;
    wp += (bytes + 255) & ~(size_t)255;
    return p;
  };
  __bf16* x2    = (__bf16*)carve((size_t)bs * D_MODEL * 2);
  __bf16* wqkv  = (__bf16*)carve((size_t)3 * D_MODEL * D_MODEL * 2);
  __bf16* wo_b  = (__bf16*)carve((size_t)D_MODEL * D_MODEL * 2);
  __bf16* w1_b  = (__bf16*)carve((size_t)DFFN * D_MODEL * 2);
  __bf16* w2_b  = (__bf16*)carve((size_t)D_MODEL * DFFN * 2);
  float*  qkv   = (float*)carve((size_t)bs * 3 * D_MODEL * 4);
  float*  sc_ws = (float*)carve((size_t)bs * NHEADS * s * 4);     // 4 MB
  float2* stats = (float2*)carve((size_t)bs * NHEADS * 4 * 8);    // 128 KB
  float*  partw = (float*)carve((size_t)bs * 4 * D_MODEL * 4);    // 4 MB
  __bf16* conc  = (__bf16*)carve((size_t)bs * D_MODEL * 2);
  float*  xres  = (float*)carve((size_t)bs * D_MODEL * 4);
  __bf16* x2b   = (__bf16*)carve((size_t)bs * D_MODEL * 2);
  __bf16* f1    = (__bf16*)carve((size_t)bs * DFFN * 2);

  // 1. Weight casts (Wq/Wk/Wv packed into [1536][512])
  Segs6 cs;
  cs.s[0] = {Wq, wqkv,                         D_MODEL * D_MODEL / 4};
  cs.s[1] = {Wk, wqkv + D_MODEL * D_MODEL,     D_MODEL * D_MODEL / 4};
  cs.s[2] = {Wv, wqkv + 2 * D_MODEL * D_MODEL, D_MODEL * D_MODEL / 4};
  cs.s[3] = {Wo, wo_b, D_MODEL * D_MODEL / 4};
  cs.s[4] = {W1, w1_b, DFFN * D_MODEL / 4};
  cs.s[5] = {W2, w2_b, D_MODEL * DFFN / 4};
  cast6<<<dim3(256, 6), 256, 0, stream>>>(cs);

  // 2. LN1 -> bf16
  ln_kernel<<<bs, 256, 0, stream>>>(x, alpha1, beta1, x2);

  // 3. Fused QKV GEMM (3-segment bias select in epilogue)
  wave_gemm<0, 0, 1><<<dim3(3 * D_MODEL / 32, bs / 32), 64, 0, stream>>>(
      x2, D_MODEL, wqkv, D_MODEL, bq, bk, bv, nullptr, qkv, 3 * D_MODEL, D_MODEL);

  // 4. Attention: scores+stats -> PV(inline softmax) -> reduce
  attn_scores<<<dim3(4, s, b), 256, 0, stream>>>(qkv, 3 * D_MODEL, cbk, mask,
                                                 sc_ws, stats, s);
  attn_pv<<<dim3(4, s, b), 256, 0, stream>>>(qkv, 3 * D_MODEL, cbv, sc_ws,
                                             stats, partw, s);
  attn_reduce<<<bs, 256, 0, stream>>>(partw, conc);

  // 5. Wo GEMM + residual(x) -> xres fp32
  wave_gemm<0, 0, 0><<<dim3(D_MODEL / 32, bs / 32), 64, 0, stream>>>(
      conc, D_MODEL, wo_b, D_MODEL, bo, nullptr, nullptr, x, xres, D_MODEL, D_MODEL);

  // 6. LN2 -> bf16
  ln_kernel<<<bs, 256, 0, stream>>>(xres, alpha2, beta2, x2b);

  // 7. FFN1 + ReLU -> f1 bf16
  wave_gemm<1, 1, 0><<<dim3(DFFN / 32, bs / 32), 64, 0, stream>>>(
      x2b, D_MODEL, w1_b, D_MODEL, b1, nullptr, nullptr, nullptr, f1, DFFN, D_MODEL);

  // 8. FFN2 + bias + residual(xres) -> d_out fp32
  wave_gemm<0, 0, 0><<<dim3(D_MODEL / 32, bs / 32), 64, 0, stream>>>(
      f1, DFFN, w2_b, DFFN, b2, nullptr, nullptr, xres, d_out, D_MODEL, DFFN);
}